// Round 2
// baseline (425.113 us; speedup 1.0000x reference)
//
#include <hip/hip_runtime.h>
#include <hip/hip_bf16.h>

typedef __attribute__((ext_vector_type(8))) short bf16x8;
typedef __attribute__((ext_vector_type(4))) short bf16x4;
typedef __attribute__((ext_vector_type(4))) float f32x4;

__device__ __forceinline__ short f2bf(float f){
  __hip_bfloat16 h = __float2bfloat16(f);
  return __builtin_bit_cast(short, h);
}
__device__ __forceinline__ float bf2f(short s){
  unsigned u = ((unsigned)(unsigned short)s) << 16;
  return __builtin_bit_cast(float, u);
}

__device__ __forceinline__ void gload_lds16(const short* g, short* l){
  __builtin_amdgcn_global_load_lds(
      (const __attribute__((address_space(1))) void*)g,
      (__attribute__((address_space(3))) void*)l, 16, 0, 0);
}

// ---------------- GroupNorm stats: one block per (batch, group) ----------------
__global__ __launch_bounds__(256) void gn_stats(const float* __restrict__ x,
                                                float* __restrict__ stats){
  int b = blockIdx.x >> 5, g = blockIdx.x & 31;
  const float4* p = (const float4*)(x + ((long long)b*512 + g*16)*4096);
  float s = 0.f, s2 = 0.f;
  for (int i = threadIdx.x; i < 16384; i += 256){
    float4 v = p[i];
    s  += v.x + v.y + v.z + v.w;
    s2 += v.x*v.x + v.y*v.y + v.z*v.z + v.w*v.w;
  }
  #pragma unroll
  for (int o = 32; o; o >>= 1){ s += __shfl_xor(s, o); s2 += __shfl_xor(s2, o); }
  __shared__ float rs[4], rs2[4];
  int wid = threadIdx.x >> 6;
  if ((threadIdx.x & 63) == 0){ rs[wid] = s; rs2[wid] = s2; }
  __syncthreads();
  if (threadIdx.x == 0){
    float S  = rs[0]+rs[1]+rs[2]+rs[3];
    float S2 = rs2[0]+rs2[1]+rs2[2]+rs2[3];
    float mean = S * (1.f/65536.f);
    float var  = S2 * (1.f/65536.f) - mean*mean;
    stats[blockIdx.x*2]   = mean;
    stats[blockIdx.x*2+1] = rsqrtf(var + 1e-6f);
  }
}

// ------------- GN apply + transpose [B,C,N] -> h bf16 [B,N,C] ------------------
__global__ __launch_bounds__(256) void gn_apply(const float* __restrict__ x,
                                                const float* __restrict__ stats,
                                                const float* __restrict__ gw,
                                                const float* __restrict__ gb,
                                                short* __restrict__ h){
  __shared__ float tile[128][65];
  int b  = blockIdx.y;
  int n0 = blockIdx.x * 64;
  int t  = threadIdx.x;
  const float* xb = x + (long long)b*512*4096;
  for (int cc = 0; cc < 4; cc++){
    int c0 = cc*128;
    #pragma unroll
    for (int r = 0; r < 128; r += 4){
      int c = r + (t >> 6);
      tile[c][t & 63] = xb[(long long)(c0+c)*4096 + n0 + (t & 63)];
    }
    __syncthreads();
    int n = t >> 2, cp = (t & 3)*32;
    short tmp[32];
    #pragma unroll
    for (int j = 0; j < 32; j++){
      int c = c0 + cp + j;
      float mean = stats[(b*32 + (c >> 4))*2];
      float rstd = stats[(b*32 + (c >> 4))*2 + 1];
      float v = (tile[cp+j][n] - mean)*rstd*gw[c] + gb[c];
      tmp[j] = f2bf(v);
    }
    long long ho = ((long long)b*4096 + n0 + n)*512 + c0 + cp;
    #pragma unroll
    for (int j2 = 0; j2 < 4; j2++){
      bf16x8 v8;
      #pragma unroll
      for (int e = 0; e < 8; e++) v8[e] = tmp[j2*8 + e];
      *(bf16x8*)&h[ho + j2*8] = v8;
    }
    __syncthreads();
  }
}

// ---------- fp32 -> bf16 conversion for all 4 weight matrices in one launch ----
__global__ __launch_bounds__(256) void f2bf_all(
    const float* __restrict__ w0, const float* __restrict__ w1,
    const float* __restrict__ w2, const float* __restrict__ w3,
    short* __restrict__ o0, short* __restrict__ o1,
    short* __restrict__ o2, short* __restrict__ o3){
  int idx = blockIdx.x*256 + threadIdx.x;   // 512 blocks; 32768 threads/matrix
  int m = idx >> 15, r = idx & 32767;
  const float* src = (m==0) ? w0 : (m==1) ? w1 : (m==2) ? w2 : w3;
  short* dst       = (m==0) ? o0 : (m==1) ? o1 : (m==2) ? o2 : o3;
  const float4* p = (const float4*)src + (long long)r*2;
  float4 a = p[0], c = p[1];
  bf16x8 v;
  v[0]=f2bf(a.x); v[1]=f2bf(a.y); v[2]=f2bf(a.z); v[3]=f2bf(a.w);
  v[4]=f2bf(c.x); v[5]=f2bf(c.y); v[6]=f2bf(c.z); v[7]=f2bf(c.w);
  *(bf16x8*)&dst[(long long)r*8] = v;
}

// ---------------- row softmax in place over bf16 rows of length 4096 -----------
__global__ __launch_bounds__(256) void softmax_rows(short* __restrict__ S){
  long long row = blockIdx.x;
  short* p = S + row*4096;
  int t = threadIdx.x;
  bf16x8 v0 = *(bf16x8*)&p[t*16];
  bf16x8 v1 = *(bf16x8*)&p[t*16 + 8];
  float f[16];
  #pragma unroll
  for (int e = 0; e < 8; e++){ f[e] = bf2f(v0[e]); f[8+e] = bf2f(v1[e]); }
  float m = f[0];
  #pragma unroll
  for (int e = 1; e < 16; e++) m = fmaxf(m, f[e]);
  #pragma unroll
  for (int o = 32; o; o >>= 1) m = fmaxf(m, __shfl_xor(m, o));
  __shared__ float red[4];
  int wid = t >> 6;
  if ((t & 63) == 0) red[wid] = m;
  __syncthreads();
  m = fmaxf(fmaxf(red[0], red[1]), fmaxf(red[2], red[3]));
  float s = 0.f;
  #pragma unroll
  for (int e = 0; e < 16; e++){ f[e] = exp2f((f[e]-m)*1.4426950408889634f); s += f[e]; }
  #pragma unroll
  for (int o = 32; o; o >>= 1) s += __shfl_xor(s, o);
  __syncthreads();
  if ((t & 63) == 0) red[wid] = s;
  __syncthreads();
  s = red[0]+red[1]+red[2]+red[3];
  float inv = 1.f/s;
  #pragma unroll
  for (int e = 0; e < 8; e++){ v0[e] = f2bf(f[e]*inv); v1[e] = f2bf(f[8+e]*inv); }
  *(bf16x8*)&p[t*16]     = v0;
  *(bf16x8*)&p[t*16 + 8] = v1;
}

// ---------------- bf16 GEMM: C = (A . B^T + bias) * scale ----------------------
// A [M][Kd] bf16 row-major; B [Nn][Kd] bf16 row-major.
// m97 structure: global_load_lds width-16 staging, linear LDS [128][32]/operand,
// single buffer, 2 barriers per K-step.
// MODE 0: bf16 out [M][Nn] (LDS-repacked coalesced stores)
// MODE 1: bf16 out transposed [Nn][M]
// MODE 2: fp32 out [Nn][M] with residual add (O-projection epilogue)
template<int MODE>
__global__ __launch_bounds__(256) void gemm_bt(
    const short* __restrict__ A, const short* __restrict__ Bw,
    const float* __restrict__ bias,
    void* __restrict__ outp, const float* __restrict__ resid,
    int M, int Nn, int Kd,
    long long sA, long long sB, long long sO, float scale)
{
  __shared__ short lds[8704];        // As[128][32] | Bs[128][32]; epilogue needs 8704
  short* As = lds;
  short* Bs = lds + 4096;

  int bz = blockIdx.z;
  const short* Ab = A + bz*sA;
  const short* Bb = Bw + bz*sB;

  int m0 = blockIdx.x*128, n0 = blockIdx.y*128;
  int t = threadIdx.x;
  int wid = t >> 6, lane = t & 63, g = lane >> 4, lr = lane & 15;
  int wr = wid >> 1, wc = wid & 1;

  // staging: thread t covers flat LDS bytes t*16 (+4096 for second half)
  int srow = t >> 2;              // 0..63
  int scol = (t & 3) * 8;         // element col 0,8,16,24
  const short* pA0 = Ab + (long long)(m0 + srow)*Kd + scol;
  const short* pA1 = pA0 + 64ll*Kd;
  const short* pB0 = Bb + (long long)(n0 + srow)*Kd + scol;
  const short* pB1 = pB0 + 64ll*Kd;
  short* lA0 = As + srow*32 + scol;   // lane-linear: byte offset == t*16
  short* lA1 = lA0 + 2048;
  short* lB0 = Bs + srow*32 + scol;
  short* lB1 = lB0 + 2048;

  f32x4 acc[4][4];
  #pragma unroll
  for (int i = 0; i < 4; i++)
    #pragma unroll
    for (int j = 0; j < 4; j++)
      acc[i][j] = f32x4{0.f,0.f,0.f,0.f};

  for (int kt = 0; kt < Kd; kt += 32){
    gload_lds16(pA0 + kt, lA0);
    gload_lds16(pA1 + kt, lA1);
    gload_lds16(pB0 + kt, lB0);
    gload_lds16(pB1 + kt, lB1);
    __syncthreads();               // compiler drains vmcnt(0) before barrier
    bf16x8 af[4], bfr[4];
    #pragma unroll
    for (int mi = 0; mi < 4; mi++)
      af[mi] = *(bf16x8*)&As[(wr*64 + mi*16 + lr)*32 + g*8];
    #pragma unroll
    for (int ni = 0; ni < 4; ni++)
      bfr[ni] = *(bf16x8*)&Bs[(wc*64 + ni*16 + lr)*32 + g*8];
    #pragma unroll
    for (int mi = 0; mi < 4; mi++)
      #pragma unroll
      for (int ni = 0; ni < 4; ni++)
        acc[mi][ni] = __builtin_amdgcn_mfma_f32_16x16x32_bf16(af[mi], bfr[ni], acc[mi][ni], 0, 0, 0);
    __syncthreads();
  }

  if (MODE == 0){
    short* outb = (short*)outp + bz*sO;
    #pragma unroll
    for (int half = 0; half < 2; half++){
      __syncthreads();
      if (wr == half){
        #pragma unroll
        for (int ni = 0; ni < 4; ni++){
          int col = wc*64 + ni*16 + lr;
          float bv2 = bias ? bias[n0 + col] : 0.f;
          #pragma unroll
          for (int mi = 0; mi < 4; mi++){
            #pragma unroll
            for (int i = 0; i < 4; i++){
              int rl = mi*16 + g*4 + i;
              lds[rl*136 + col] = f2bf((acc[mi][ni][i] + bv2)*scale);
            }
          }
        }
      }
      __syncthreads();
      int rl = t >> 2, ccw = (t & 3)*32;
      long long gro = (long long)(m0 + half*64 + rl)*Nn + n0 + ccw;
      bf16x8* dst = (bf16x8*)&outb[gro];
      bf16x8* srcp = (bf16x8*)&lds[rl*136 + ccw];
      dst[0] = srcp[0]; dst[1] = srcp[1]; dst[2] = srcp[2]; dst[3] = srcp[3];
    }
  } else if (MODE == 1){
    short* outb = (short*)outp + bz*sO;
    #pragma unroll
    for (int ni = 0; ni < 4; ni++){
      int col = n0 + wc*64 + ni*16 + lr;
      float bv2 = bias ? bias[col] : 0.f;
      #pragma unroll
      for (int mi = 0; mi < 4; mi++){
        int row = m0 + wr*64 + mi*16 + g*4;
        bf16x4 pk;
        #pragma unroll
        for (int i = 0; i < 4; i++) pk[i] = f2bf((acc[mi][ni][i] + bv2)*scale);
        *(bf16x4*)&outb[(long long)col*M + row] = pk;
      }
    }
  } else {
    float* outb = (float*)outp + bz*sO;
    const float* rx = resid + bz*sO;
    #pragma unroll
    for (int ni = 0; ni < 4; ni++){
      int col = n0 + wc*64 + ni*16 + lr;
      float bv2 = bias[col];
      #pragma unroll
      for (int mi = 0; mi < 4; mi++){
        int row = m0 + wr*64 + mi*16 + g*4;
        long long off = (long long)col*M + row;
        float4 xr = *(const float4*)&rx[off];
        float4 o;
        o.x = acc[mi][ni][0] + bv2 + xr.x;
        o.y = acc[mi][ni][1] + bv2 + xr.y;
        o.z = acc[mi][ni][2] + bv2 + xr.z;
        o.w = acc[mi][ni][3] + bv2 + xr.w;
        *(float4*)&outb[off] = o;
      }
    }
  }
}

extern "C" void kernel_launch(void* const* d_in, const int* in_sizes, int n_in,
                              void* d_out, int out_size, void* d_ws, size_t ws_size,
                              hipStream_t stream)
{
  const float* x   = (const float*)d_in[0];
  const float* gnw = (const float*)d_in[1];
  const float* gnb = (const float*)d_in[2];
  const float* Wq  = (const float*)d_in[3];
  const float* bq  = (const float*)d_in[4];
  const float* Wk  = (const float*)d_in[5];
  const float* bk  = (const float*)d_in[6];
  const float* Wv  = (const float*)d_in[7];
  const float* bvp = (const float*)d_in[8];
  const float* Wo  = (const float*)d_in[9];
  const float* bo  = (const float*)d_in[10];
  float* out = (float*)d_out;

  char* ws = (char*)d_ws;
  const size_t MB = 1ull << 20;
  short* h    = (short*)(ws);
  short* q    = (short*)(ws + 16*MB);
  short* kmat = (short*)(ws + 32*MB);
  short* vt   = (short*)(ws + 48*MB);
  short* ao   = (short*)(ws + 64*MB);
  short* wqb  = (short*)(ws + 80*MB);
  short* wkb  = wqb + 262144;
  short* wvb  = wkb + 262144;
  short* wob  = wvb + 262144;
  float* stats= (float*)(ws + 82*MB);
  short* S    = (short*)(ws + 84*MB);   // 128 MB (full path)

  dim3 blk(256);
  gn_stats<<<dim3(128), blk, 0, stream>>>(x, stats);
  gn_apply<<<dim3(64,4), blk, 0, stream>>>(x, stats, gnw, gnb, h);
  f2bf_all<<<dim3(512), blk, 0, stream>>>(Wq, Wk, Wv, Wo, wqb, wkb, wvb, wob);

  const long long sTok = 4096ll*512;
  const float qscale = 0.044194173824159216f;  // 1/sqrt(512)

  // Q (scale folded), K, V(transposed out)
  gemm_bt<0><<<dim3(32,4,4),  blk, 0, stream>>>(h, wqb, bq,  q,    nullptr, 4096, 512, 512, sTok, 0, sTok, qscale);
  gemm_bt<0><<<dim3(32,4,4),  blk, 0, stream>>>(h, wkb, bk,  kmat, nullptr, 4096, 512, 512, sTok, 0, sTok, 1.f);
  gemm_bt<1><<<dim3(32,4,4),  blk, 0, stream>>>(h, wvb, bvp, vt,   nullptr, 4096, 512, 512, sTok, 0, sTok, 1.f);

  if (ws_size >= 212*MB){
    gemm_bt<0><<<dim3(32,32,4), blk, 0, stream>>>(q, kmat, nullptr, S, nullptr, 4096, 4096, 512, sTok, sTok, 4096ll*4096, 1.f);
    softmax_rows<<<dim3(16384), blk, 0, stream>>>(S);
    gemm_bt<0><<<dim3(32,4,4),  blk, 0, stream>>>(S, vt, nullptr, ao, nullptr, 4096, 512, 4096, 4096ll*4096, sTok, sTok, 1.f);
  } else {
    // per-batch fallback: S slab reused, needs only 84MB + 32MB of ws
    for (int b = 0; b < 4; b++){
      gemm_bt<0><<<dim3(32,32,1), blk, 0, stream>>>(q + b*sTok, kmat + b*sTok, nullptr, S, nullptr, 4096, 4096, 512, 0, 0, 0, 1.f);
      softmax_rows<<<dim3(4096), blk, 0, stream>>>(S);
      gemm_bt<0><<<dim3(32,4,1),  blk, 0, stream>>>(S, vt + b*sTok, nullptr, ao + b*sTok, nullptr, 4096, 512, 4096, 0, 0, 0, 1.f);
    }
  }

  // O-projection + bias + residual + transpose to [B, C, N] fp32
  gemm_bt<2><<<dim3(32,4,4), blk, 0, stream>>>(ao, wob, bo, out, x, 4096, 512, 512, sTok, 0, sTok, 1.f);
}

// Round 3
// 352.705 us; speedup vs baseline: 1.2053x; 1.2053x over previous
//
#include <hip/hip_runtime.h>
#include <hip/hip_bf16.h>

typedef __attribute__((ext_vector_type(8))) short bf16x8;
typedef __attribute__((ext_vector_type(4))) short bf16x4;
typedef __attribute__((ext_vector_type(4))) float f32x4;

__device__ __forceinline__ short f2bf(float f){
  __hip_bfloat16 h = __float2bfloat16(f);
  return __builtin_bit_cast(short, h);
}
__device__ __forceinline__ float bf2f(short s){
  unsigned u = ((unsigned)(unsigned short)s) << 16;
  return __builtin_bit_cast(float, u);
}

__device__ __forceinline__ void gload_lds16(const short* g, char* l){
  __builtin_amdgcn_global_load_lds(
      (const __attribute__((address_space(1))) void*)g,
      (__attribute__((address_space(3))) void*)l, 16, 0, 0);
}

// ---------------- GroupNorm stats: one block per (batch, group) ----------------
__global__ __launch_bounds__(256) void gn_stats(const float* __restrict__ x,
                                                float* __restrict__ stats){
  int b = blockIdx.x >> 5, g = blockIdx.x & 31;
  const float4* p = (const float4*)(x + ((long long)b*512 + g*16)*4096);
  float s = 0.f, s2 = 0.f;
  for (int i = threadIdx.x; i < 16384; i += 256){
    float4 v = p[i];
    s  += v.x + v.y + v.z + v.w;
    s2 += v.x*v.x + v.y*v.y + v.z*v.z + v.w*v.w;
  }
  #pragma unroll
  for (int o = 32; o; o >>= 1){ s += __shfl_xor(s, o); s2 += __shfl_xor(s2, o); }
  __shared__ float rs[4], rs2[4];
  int wid = threadIdx.x >> 6;
  if ((threadIdx.x & 63) == 0){ rs[wid] = s; rs2[wid] = s2; }
  __syncthreads();
  if (threadIdx.x == 0){
    float S  = rs[0]+rs[1]+rs[2]+rs[3];
    float S2 = rs2[0]+rs2[1]+rs2[2]+rs2[3];
    float mean = S * (1.f/65536.f);
    float var  = S2 * (1.f/65536.f) - mean*mean;
    stats[blockIdx.x*2]   = mean;
    stats[blockIdx.x*2+1] = rsqrtf(var + 1e-6f);
  }
}

// ------------- GN apply + transpose [B,C,N] -> h bf16 [B,N,C] ------------------
__global__ __launch_bounds__(256) void gn_apply(const float* __restrict__ x,
                                                const float* __restrict__ stats,
                                                const float* __restrict__ gw,
                                                const float* __restrict__ gb,
                                                short* __restrict__ h){
  __shared__ float tile[128][65];
  int b  = blockIdx.y;
  int n0 = blockIdx.x * 64;
  int t  = threadIdx.x;
  const float* xb = x + (long long)b*512*4096;
  for (int cc = 0; cc < 4; cc++){
    int c0 = cc*128;
    #pragma unroll
    for (int r = 0; r < 128; r += 4){
      int c = r + (t >> 6);
      tile[c][t & 63] = xb[(long long)(c0+c)*4096 + n0 + (t & 63)];
    }
    __syncthreads();
    int n = t >> 2, cp = (t & 3)*32;
    short tmp[32];
    #pragma unroll
    for (int j = 0; j < 32; j++){
      int c = c0 + cp + j;
      float mean = stats[(b*32 + (c >> 4))*2];
      float rstd = stats[(b*32 + (c >> 4))*2 + 1];
      float v = (tile[cp+j][n] - mean)*rstd*gw[c] + gb[c];
      tmp[j] = f2bf(v);
    }
    long long ho = ((long long)b*4096 + n0 + n)*512 + c0 + cp;
    #pragma unroll
    for (int j2 = 0; j2 < 4; j2++){
      bf16x8 v8;
      #pragma unroll
      for (int e = 0; e < 8; e++) v8[e] = tmp[j2*8 + e];
      *(bf16x8*)&h[ho + j2*8] = v8;
    }
    __syncthreads();
  }
}

// ---------- fp32 -> bf16 conversion for all 4 weight matrices in one launch ----
__global__ __launch_bounds__(256) void f2bf_all(
    const float* __restrict__ w0, const float* __restrict__ w1,
    const float* __restrict__ w2, const float* __restrict__ w3,
    short* __restrict__ o0, short* __restrict__ o1,
    short* __restrict__ o2, short* __restrict__ o3){
  int idx = blockIdx.x*256 + threadIdx.x;
  int m = idx >> 15, r = idx & 32767;
  const float* src = (m==0) ? w0 : (m==1) ? w1 : (m==2) ? w2 : w3;
  short* dst       = (m==0) ? o0 : (m==1) ? o1 : (m==2) ? o2 : o3;
  const float4* p = (const float4*)src + (long long)r*2;
  float4 a = p[0], c = p[1];
  bf16x8 v;
  v[0]=f2bf(a.x); v[1]=f2bf(a.y); v[2]=f2bf(a.z); v[3]=f2bf(a.w);
  v[4]=f2bf(c.x); v[5]=f2bf(c.y); v[6]=f2bf(c.z); v[7]=f2bf(c.w);
  *(bf16x8*)&dst[(long long)r*8] = v;
}

// ---------------- row softmax in place over bf16 rows of length 4096 -----------
__global__ __launch_bounds__(256) void softmax_rows(short* __restrict__ S){
  long long row = blockIdx.x;
  short* p = S + row*4096;
  int t = threadIdx.x;
  bf16x8 v0 = *(bf16x8*)&p[t*16];
  bf16x8 v1 = *(bf16x8*)&p[t*16 + 8];
  float f[16];
  #pragma unroll
  for (int e = 0; e < 8; e++){ f[e] = bf2f(v0[e]); f[8+e] = bf2f(v1[e]); }
  float m = f[0];
  #pragma unroll
  for (int e = 1; e < 16; e++) m = fmaxf(m, f[e]);
  #pragma unroll
  for (int o = 32; o; o >>= 1) m = fmaxf(m, __shfl_xor(m, o));
  __shared__ float red[4];
  int wid = t >> 6;
  if ((t & 63) == 0) red[wid] = m;
  __syncthreads();
  m = fmaxf(fmaxf(red[0], red[1]), fmaxf(red[2], red[3]));
  float s = 0.f;
  #pragma unroll
  for (int e = 0; e < 16; e++){ f[e] = exp2f((f[e]-m)*1.4426950408889634f); s += f[e]; }
  #pragma unroll
  for (int o = 32; o; o >>= 1) s += __shfl_xor(s, o);
  __syncthreads();
  if ((t & 63) == 0) red[wid] = s;
  __syncthreads();
  s = red[0]+red[1]+red[2]+red[3];
  float inv = 1.f/s;
  #pragma unroll
  for (int e = 0; e < 8; e++){ v0[e] = f2bf(f[e]*inv); v1[e] = f2bf(f[8+e]*inv); }
  *(bf16x8*)&p[t*16]     = v0;
  *(bf16x8*)&p[t*16 + 8] = v1;
}

// ============ 256xBN bf16 GEMM: C = (A . B^T + bias) * scale ==================
// A [M][Kd], B [Nn][Kd] bf16 row-major. BK=64, 8 waves (512 thr), dbuf LDS,
// counted-vmcnt pipeline, XOR-swizzled LDS (linear gload dest + pre-swizzled
// global source + swizzled ds_read). Swizzle: byte ^= ((byte>>7)&7)<<4.
// MODE 0: bf16 out [M][Nn] (swapped-operand MFMA, direct bf16x4 col-stores)
// MODE 1: bf16 out transposed [Nn][M]
// MODE 2: fp32 out [Nn][M] + residual add
template<int MODE, int BN>
__global__ __launch_bounds__(512, 2) void gemm256(
    const short* __restrict__ A, const short* __restrict__ Bw,
    const float* __restrict__ bias,
    void* __restrict__ outp, const float* __restrict__ resid,
    int M, int Nn, int Kd,
    long long sA, long long sB, long long sO, float scale)
{
  constexpr int BROUNDS = BN/64;            // staging rounds for B (4 or 2)
  constexpr int LOADS   = 4 + BROUNDS;      // gloads / thread / K-tile
  constexpr int WM = (BN==256) ? 128 : 64;  // per-wave rows
  constexpr int WN = 64;                    // per-wave cols
  constexpr int WAVES_N = BN/WN;
  constexpr int MF = WM/16, NF = WN/16;
  constexpr int ASZ = 32768, BSZ = BN*128;  // bytes per K-tile per operand
  extern __shared__ char smem[];

  const int bz = blockIdx.z;
  const short* Ab = A + bz*sA;
  const short* Bb = Bw + bz*sB;
  const int m0 = blockIdx.x*256, n0 = blockIdx.y*BN;
  const int t = threadIdx.x;
  const int lane = t & 63, wid = t >> 6;
  const int g = lane >> 4, lr = lane & 15;
  const int wr = wid / WAVES_N, wc = wid % WAVES_N;

  // ---- staging addresses (pre-swizzled global source, linear LDS dest) ----
  const int rsub = t >> 3;                          // 0..63 (row within round)
  const int chunkEl = (((t & 7) ^ (rsub & 7))) * 8; // swizzled 16B-chunk source
  const short* gA[4]; const short* gB[BROUNDS];
  #pragma unroll
  for (int j = 0; j < 4; j++)
    gA[j] = Ab + (long long)(m0 + j*64 + rsub)*Kd + chunkEl;
  #pragma unroll
  for (int j = 0; j < BROUNDS; j++)
    gB[j] = Bb + (long long)(n0 + j*64 + rsub)*Kd + chunkEl;
  const int tb = t*16;

  // ---- swizzled ds_read offsets ----
  const int rowAbyte = (wr*WM + lr)*128;
  const int rowBbyte = (wc*WN + lr)*128;
  const int ch0 = ((g)     ^ (lr & 7)) << 4;   // ks=0 chunk
  const int ch1 = ((4 + g) ^ (lr & 7)) << 4;   // ks=1 chunk

  f32x4 acc[MF][NF];
  #pragma unroll
  for (int i = 0; i < MF; i++)
    #pragma unroll
    for (int j = 0; j < NF; j++)
      acc[i][j] = f32x4{0.f,0.f,0.f,0.f};

  const int NT = Kd >> 6;

  auto STAGE = [&](int tile, int buf){
    char* base = smem + buf*(ASZ+BSZ);
    const int kt = tile*64;
    #pragma unroll
    for (int j = 0; j < 4; j++)
      gload_lds16(gA[j] + kt, base + j*8192 + tb);
    #pragma unroll
    for (int j = 0; j < BROUNDS; j++)
      gload_lds16(gB[j] + kt, base + ASZ + j*8192 + tb);
  };

  STAGE(0, 0);
  STAGE(1, 1);
  if constexpr (LOADS == 8) asm volatile("s_waitcnt vmcnt(8)" ::: "memory");
  else                      asm volatile("s_waitcnt vmcnt(6)" ::: "memory");
  __builtin_amdgcn_s_barrier();

  for (int it = 0; it < NT; ++it){
    char* base = smem + (it & 1)*(ASZ+BSZ);
    bf16x8 av[MF][2], bv[NF][2];
    #pragma unroll
    for (int ni = 0; ni < NF; ni++){
      bv[ni][0] = *(const bf16x8*)(base + ASZ + rowBbyte + ni*2048 + ch0);
      bv[ni][1] = *(const bf16x8*)(base + ASZ + rowBbyte + ni*2048 + ch1);
    }
    #pragma unroll
    for (int mi = 0; mi < MF; mi++){
      av[mi][0] = *(const bf16x8*)(base + rowAbyte + mi*2048 + ch0);
      av[mi][1] = *(const bf16x8*)(base + rowAbyte + mi*2048 + ch1);
    }
    // all reads serviced before any wave's next stage can land
    asm volatile("s_waitcnt lgkmcnt(0)" ::: "memory");
    __builtin_amdgcn_sched_barrier(0);
    __builtin_amdgcn_s_barrier();

    if (it + 2 < NT) STAGE(it + 2, it & 1);

    #pragma unroll
    for (int mi = 0; mi < MF; mi++)
      #pragma unroll
      for (int ni = 0; ni < NF; ni++)
        #pragma unroll
        for (int ks = 0; ks < 2; ks++){
          if constexpr (MODE == 0)
            acc[mi][ni] = __builtin_amdgcn_mfma_f32_16x16x32_bf16(bv[ni][ks], av[mi][ks], acc[mi][ni], 0, 0, 0);
          else
            acc[mi][ni] = __builtin_amdgcn_mfma_f32_16x16x32_bf16(av[mi][ks], bv[ni][ks], acc[mi][ni], 0, 0, 0);
        }

    if (it + 2 < NT){
      if constexpr (LOADS == 8) asm volatile("s_waitcnt vmcnt(8)" ::: "memory");
      else                      asm volatile("s_waitcnt vmcnt(6)" ::: "memory");
    } else {
      asm volatile("s_waitcnt vmcnt(0)" ::: "memory");
    }
    __builtin_amdgcn_s_barrier();
  }

  if constexpr (MODE == 0){
    // swapped operands: lane dim = rows, reg dim = 4 consecutive cols
    short* outb = (short*)outp + bz*sO;
    const bool hb = (bias != nullptr);
    #pragma unroll
    for (int mi = 0; mi < MF; mi++){
      int row = m0 + wr*WM + mi*16 + lr;
      #pragma unroll
      for (int ni = 0; ni < NF; ni++){
        int col = n0 + wc*WN + ni*16 + g*4;
        float b0=0.f,b1=0.f,b2=0.f,b3=0.f;
        if (hb){ float4 bb = *(const float4*)&bias[col]; b0=bb.x; b1=bb.y; b2=bb.z; b3=bb.w; }
        bf16x4 pk;
        pk[0] = f2bf((acc[mi][ni][0] + b0)*scale);
        pk[1] = f2bf((acc[mi][ni][1] + b1)*scale);
        pk[2] = f2bf((acc[mi][ni][2] + b2)*scale);
        pk[3] = f2bf((acc[mi][ni][3] + b3)*scale);
        *(bf16x4*)&outb[(long long)row*Nn + col] = pk;
      }
    }
  } else if constexpr (MODE == 1){
    short* outb = (short*)outp + bz*sO;
    #pragma unroll
    for (int ni = 0; ni < NF; ni++){
      int col = n0 + wc*WN + ni*16 + lr;
      float bv2 = bias ? bias[col] : 0.f;
      #pragma unroll
      for (int mi = 0; mi < MF; mi++){
        int row = m0 + wr*WM + mi*16 + g*4;
        bf16x4 pk;
        #pragma unroll
        for (int i = 0; i < 4; i++) pk[i] = f2bf((acc[mi][ni][i] + bv2)*scale);
        *(bf16x4*)&outb[(long long)col*M + row] = pk;
      }
    }
  } else {
    float* outb = (float*)outp + bz*sO;
    const float* rx = resid + bz*sO;
    #pragma unroll
    for (int ni = 0; ni < NF; ni++){
      int col = n0 + wc*WN + ni*16 + lr;
      float bv2 = bias[col];
      #pragma unroll
      for (int mi = 0; mi < MF; mi++){
        int row = m0 + wr*WM + mi*16 + g*4;
        long long off = (long long)col*M + row;
        float4 xr = *(const float4*)&rx[off];
        float4 o;
        o.x = acc[mi][ni][0] + bv2 + xr.x;
        o.y = acc[mi][ni][1] + bv2 + xr.y;
        o.z = acc[mi][ni][2] + bv2 + xr.z;
        o.w = acc[mi][ni][3] + bv2 + xr.w;
        *(float4*)&outb[off] = o;
      }
    }
  }
}

extern "C" void kernel_launch(void* const* d_in, const int* in_sizes, int n_in,
                              void* d_out, int out_size, void* d_ws, size_t ws_size,
                              hipStream_t stream)
{
  const float* x   = (const float*)d_in[0];
  const float* gnw = (const float*)d_in[1];
  const float* gnb = (const float*)d_in[2];
  const float* Wq  = (const float*)d_in[3];
  const float* bq  = (const float*)d_in[4];
  const float* Wk  = (const float*)d_in[5];
  const float* bk  = (const float*)d_in[6];
  const float* Wv  = (const float*)d_in[7];
  const float* bvp = (const float*)d_in[8];
  const float* Wo  = (const float*)d_in[9];
  const float* bo  = (const float*)d_in[10];
  float* out = (float*)d_out;

  char* ws = (char*)d_ws;
  const size_t MB = 1ull << 20;
  short* h    = (short*)(ws);
  short* q    = (short*)(ws + 16*MB);
  short* kmat = (short*)(ws + 32*MB);
  short* vt   = (short*)(ws + 48*MB);
  short* ao   = (short*)(ws + 64*MB);
  short* wqb  = (short*)(ws + 80*MB);
  short* wkb  = wqb + 262144;
  short* wvb  = wkb + 262144;
  short* wob  = wvb + 262144;
  float* stats= (float*)(ws + 82*MB);
  short* S    = (short*)(ws + 84*MB);   // 128 MB (full path)

  // allow >64KB dynamic LDS (idempotent, not a stream op)
  const int LDS256 = 131072, LDS128 = 98304;
  hipFuncSetAttribute(reinterpret_cast<const void*>(&gemm256<0,256>),
                      hipFuncAttributeMaxDynamicSharedMemorySize, LDS256);
  hipFuncSetAttribute(reinterpret_cast<const void*>(&gemm256<0,128>),
                      hipFuncAttributeMaxDynamicSharedMemorySize, LDS128);
  hipFuncSetAttribute(reinterpret_cast<const void*>(&gemm256<1,128>),
                      hipFuncAttributeMaxDynamicSharedMemorySize, LDS128);
  hipFuncSetAttribute(reinterpret_cast<const void*>(&gemm256<2,128>),
                      hipFuncAttributeMaxDynamicSharedMemorySize, LDS128);

  dim3 blk(256);
  dim3 blk512(512);
  gn_stats<<<dim3(128), blk, 0, stream>>>(x, stats);
  gn_apply<<<dim3(64,4), blk, 0, stream>>>(x, stats, gnw, gnb, h);
  f2bf_all<<<dim3(512), blk, 0, stream>>>(Wq, Wk, Wv, Wo, wqb, wkb, wvb, wob);

  const long long sTok = 4096ll*512;
  const float qscale = 0.044194173824159216f;  // 1/sqrt(512)

  // Q (scale folded), K, V(transposed out)
  gemm256<0,128><<<dim3(16,4,4), blk512, LDS128, stream>>>(h, wqb, bq,  q,    nullptr, 4096, 512, 512, sTok, 0, sTok, qscale);
  gemm256<0,128><<<dim3(16,4,4), blk512, LDS128, stream>>>(h, wkb, bk,  kmat, nullptr, 4096, 512, 512, sTok, 0, sTok, 1.f);
  gemm256<1,128><<<dim3(16,4,4), blk512, LDS128, stream>>>(h, wvb, bvp, vt,   nullptr, 4096, 512, 512, sTok, 0, sTok, 1.f);

  if (ws_size >= 212*MB){
    gemm256<0,256><<<dim3(16,16,4), blk512, LDS256, stream>>>(q, kmat, nullptr, S, nullptr, 4096, 4096, 512, sTok, sTok, 4096ll*4096, 1.f);
    softmax_rows<<<dim3(16384), blk, 0, stream>>>(S);
    gemm256<0,128><<<dim3(16,4,4), blk512, LDS128, stream>>>(S, vt, nullptr, ao, nullptr, 4096, 512, 4096, 4096ll*4096, sTok, sTok, 1.f);
  } else {
    for (int b = 0; b < 4; b++){
      gemm256<0,256><<<dim3(16,16,1), blk512, LDS256, stream>>>(q + b*sTok, kmat + b*sTok, nullptr, S, nullptr, 4096, 4096, 512, 0, 0, 0, 1.f);
      softmax_rows<<<dim3(4096), blk, 0, stream>>>(S);
      gemm256<0,128><<<dim3(16,4,1), blk512, LDS128, stream>>>(S, vt + b*sTok, nullptr, ao + b*sTok, nullptr, 4096, 512, 4096, 0, 0, 0, 1.f);
    }
  }

  // O-projection + bias + residual + transpose to [B, C, N] fp32
  gemm256<2,128><<<dim3(16,4,4), blk512, LDS128, stream>>>(ao, wob, bo, out, x, 4096, 512, 512, sTok, 0, sTok, 1.f);
}

// Round 4
// 339.957 us; speedup vs baseline: 1.2505x; 1.0375x over previous
//
#include <hip/hip_runtime.h>
#include <hip/hip_bf16.h>

typedef __attribute__((ext_vector_type(8))) short bf16x8;
typedef __attribute__((ext_vector_type(4))) short bf16x4;
typedef __attribute__((ext_vector_type(4))) float f32x4;

__device__ __forceinline__ short f2bf(float f){
  __hip_bfloat16 h = __float2bfloat16(f);
  return __builtin_bit_cast(short, h);
}
__device__ __forceinline__ float bf2f(short s){
  unsigned u = ((unsigned)(unsigned short)s) << 16;
  return __builtin_bit_cast(float, u);
}

__device__ __forceinline__ void gload_lds16(const short* g, char* l){
  __builtin_amdgcn_global_load_lds(
      (const __attribute__((address_space(1))) void*)g,
      (__attribute__((address_space(3))) void*)l, 16, 0, 0);
}

// ---------------- GroupNorm stats: one block per (batch, group) ----------------
__global__ __launch_bounds__(256) void gn_stats(const float* __restrict__ x,
                                                float* __restrict__ stats){
  int b = blockIdx.x >> 5, g = blockIdx.x & 31;
  const float4* p = (const float4*)(x + ((long long)b*512 + g*16)*4096);
  float s = 0.f, s2 = 0.f;
  for (int i = threadIdx.x; i < 16384; i += 256){
    float4 v = p[i];
    s  += v.x + v.y + v.z + v.w;
    s2 += v.x*v.x + v.y*v.y + v.z*v.z + v.w*v.w;
  }
  #pragma unroll
  for (int o = 32; o; o >>= 1){ s += __shfl_xor(s, o); s2 += __shfl_xor(s2, o); }
  __shared__ float rs[4], rs2[4];
  int wid = threadIdx.x >> 6;
  if ((threadIdx.x & 63) == 0){ rs[wid] = s; rs2[wid] = s2; }
  __syncthreads();
  if (threadIdx.x == 0){
    float S  = rs[0]+rs[1]+rs[2]+rs[3];
    float S2 = rs2[0]+rs2[1]+rs2[2]+rs2[3];
    float mean = S * (1.f/65536.f);
    float var  = S2 * (1.f/65536.f) - mean*mean;
    stats[blockIdx.x*2]   = mean;
    stats[blockIdx.x*2+1] = rsqrtf(var + 1e-6f);
  }
}

// ------------- GN apply + transpose [B,C,N] -> h bf16 [B,N,C] ------------------
__global__ __launch_bounds__(256) void gn_apply(const float* __restrict__ x,
                                                const float* __restrict__ stats,
                                                const float* __restrict__ gw,
                                                const float* __restrict__ gb,
                                                short* __restrict__ h){
  __shared__ float tile[128][65];
  int b  = blockIdx.y;
  int n0 = blockIdx.x * 64;
  int t  = threadIdx.x;
  const float* xb = x + (long long)b*512*4096;
  for (int cc = 0; cc < 4; cc++){
    int c0 = cc*128;
    #pragma unroll
    for (int r = 0; r < 128; r += 4){
      int c = r + (t >> 6);
      tile[c][t & 63] = xb[(long long)(c0+c)*4096 + n0 + (t & 63)];
    }
    __syncthreads();
    int n = t >> 2, cp = (t & 3)*32;
    short tmp[32];
    #pragma unroll
    for (int j = 0; j < 32; j++){
      int c = c0 + cp + j;
      float mean = stats[(b*32 + (c >> 4))*2];
      float rstd = stats[(b*32 + (c >> 4))*2 + 1];
      float v = (tile[cp+j][n] - mean)*rstd*gw[c] + gb[c];
      tmp[j] = f2bf(v);
    }
    long long ho = ((long long)b*4096 + n0 + n)*512 + c0 + cp;
    #pragma unroll
    for (int j2 = 0; j2 < 4; j2++){
      bf16x8 v8;
      #pragma unroll
      for (int e = 0; e < 8; e++) v8[e] = tmp[j2*8 + e];
      *(bf16x8*)&h[ho + j2*8] = v8;
    }
    __syncthreads();
  }
}

// ---------- fp32 -> bf16 conversion for all 4 weight matrices in one launch ----
__global__ __launch_bounds__(256) void f2bf_all(
    const float* __restrict__ w0, const float* __restrict__ w1,
    const float* __restrict__ w2, const float* __restrict__ w3,
    short* __restrict__ o0, short* __restrict__ o1,
    short* __restrict__ o2, short* __restrict__ o3){
  int idx = blockIdx.x*256 + threadIdx.x;
  int m = idx >> 15, r = idx & 32767;
  const float* src = (m==0) ? w0 : (m==1) ? w1 : (m==2) ? w2 : w3;
  short* dst       = (m==0) ? o0 : (m==1) ? o1 : (m==2) ? o2 : o3;
  const float4* p = (const float4*)src + (long long)r*2;
  float4 a = p[0], c = p[1];
  bf16x8 v;
  v[0]=f2bf(a.x); v[1]=f2bf(a.y); v[2]=f2bf(a.z); v[3]=f2bf(a.w);
  v[4]=f2bf(c.x); v[5]=f2bf(c.y); v[6]=f2bf(c.z); v[7]=f2bf(c.w);
  *(bf16x8*)&dst[(long long)r*8] = v;
}

// ---------------- row softmax in place over bf16 rows of length 4096 -----------
__global__ __launch_bounds__(256) void softmax_rows(short* __restrict__ S){
  long long row = blockIdx.x;
  short* p = S + row*4096;
  int t = threadIdx.x;
  bf16x8 v0 = *(bf16x8*)&p[t*16];
  bf16x8 v1 = *(bf16x8*)&p[t*16 + 8];
  float f[16];
  #pragma unroll
  for (int e = 0; e < 8; e++){ f[e] = bf2f(v0[e]); f[8+e] = bf2f(v1[e]); }
  float m = f[0];
  #pragma unroll
  for (int e = 1; e < 16; e++) m = fmaxf(m, f[e]);
  #pragma unroll
  for (int o = 32; o; o >>= 1) m = fmaxf(m, __shfl_xor(m, o));
  __shared__ float red[4];
  int wid = t >> 6;
  if ((t & 63) == 0) red[wid] = m;
  __syncthreads();
  m = fmaxf(fmaxf(red[0], red[1]), fmaxf(red[2], red[3]));
  float s = 0.f;
  #pragma unroll
  for (int e = 0; e < 16; e++){ f[e] = exp2f((f[e]-m)*1.4426950408889634f); s += f[e]; }
  #pragma unroll
  for (int o = 32; o; o >>= 1) s += __shfl_xor(s, o);
  __syncthreads();
  if ((t & 63) == 0) red[wid] = s;
  __syncthreads();
  s = red[0]+red[1]+red[2]+red[3];
  float inv = 1.f/s;
  #pragma unroll
  for (int e = 0; e < 8; e++){ v0[e] = f2bf(f[e]*inv); v1[e] = f2bf(f[8+e]*inv); }
  *(bf16x8*)&p[t*16]     = v0;
  *(bf16x8*)&p[t*16 + 8] = v1;
}

// =================== 8-phase 256xBN bf16 GEMM (T2+T3+T4+T5) ===================
// C[M][Nn] = A[M][Kd] . B[Nn][Kd]^T * scale, bf16 out, swapped-operand MFMA.
// 512 thr / 8 waves. BK=64, 2 K-tiles per iteration, 8 phases, counted vmcnt.
#define READ_A8(QM, BASE) do{                                          \
  _Pragma("unroll")                                                    \
  for (int _i = 0; _i < MF2; _i++){                                    \
    _Pragma("unroll")                                                  \
    for (int _ks = 0; _ks < 2; _ks++)                                  \
      av[_i][_ks] = *(const bf16x8*)((BASE) + roA[(QM)*MF2+_i] +       \
                     (((_ks*4+g) ^ swA[(QM)*MF2+_i])<<4));             \
  } }while(0)

#define READ_B4(QN, BASE) do{                                          \
  _Pragma("unroll")                                                    \
  for (int _j = 0; _j < 2; _j++){                                      \
    _Pragma("unroll")                                                  \
    for (int _ks = 0; _ks < 2; _ks++)                                  \
      bv[(QN)*2+_j][_ks] = *(const bf16x8*)((BASE) + roB[(QN)*2+_j] +  \
                     (((_ks*4+g) ^ swB[(QN)*2+_j])<<4));               \
  } }while(0)

#define MFMA_Q(QM, QN) do{                                             \
  _Pragma("unroll")                                                    \
  for (int _i = 0; _i < MF2; _i++)                                     \
    _Pragma("unroll")                                                  \
    for (int _j = 0; _j < 2; _j++)                                     \
      _Pragma("unroll")                                                \
      for (int _ks = 0; _ks < 2; _ks++)                                \
        acc[(QM)*MF2+_i][(QN)*2+_j] =                                  \
          __builtin_amdgcn_mfma_f32_16x16x32_bf16(bv[(QN)*2+_j][_ks],  \
            av[_i][_ks], acc[(QM)*MF2+_i][(QN)*2+_j], 0,0,0);          \
  }while(0)

#define STAGE_A(BUF, H, KT) do{                                        \
  char* _d = smem + (BUF)*BUFSZ + (H)*16384 + t*16;                    \
  const short* _s = pA0 + (H)*128*KdLL + (KT)*64;                      \
  gload_lds16(_s, _d);                                                 \
  gload_lds16(_s + 64*KdLL, _d + 8192);                                \
}while(0)

#define STAGE_B(BUF, H, KT) do{                                        \
  char* _d = smem + (BUF)*BUFSZ + ABUF + (H)*BHALF + t*16;             \
  const short* _s = pB0 + (H)*RB*KdLL + (KT)*64;                       \
  gload_lds16(_s, _d);                                                 \
  if constexpr (LB == 2) gload_lds16(_s + 64*KdLL, _d + 8192);         \
}while(0)

#define WAITV_STEADY() do{                                             \
  if constexpr (LB == 2) asm volatile("s_waitcnt vmcnt(4)" ::: "memory"); \
  else                   asm volatile("s_waitcnt vmcnt(2)" ::: "memory"); \
}while(0)

#define PH_BEGIN()                                                     \
  __builtin_amdgcn_sched_barrier(0);                                   \
  __builtin_amdgcn_s_barrier();                                        \
  __builtin_amdgcn_sched_barrier(0);                                   \
  asm volatile("s_waitcnt lgkmcnt(0)" ::: "memory");                   \
  __builtin_amdgcn_sched_barrier(0);                                   \
  __builtin_amdgcn_s_setprio(1)

#define PH_END()                                                       \
  __builtin_amdgcn_s_setprio(0);                                       \
  __builtin_amdgcn_sched_barrier(0);                                   \
  __builtin_amdgcn_s_barrier()

template<int BN>
__global__ __launch_bounds__(512, 2) void gemm8p(
    const short* __restrict__ A, const short* __restrict__ Bw,
    short* __restrict__ outp,
    int Nn, int Kd,
    long long sA, long long sB, long long sO, float scale)
{
  constexpr int WN = 64;
  constexpr int WARPS_N = BN/WN;            // 4 (BN=256) or 2 (BN=128)
  constexpr int WARPS_M = 8/WARPS_N;        // 2 or 4
  constexpr int WM = 256/WARPS_M;           // 128 or 64
  constexpr int MF = WM/16;                 // 8 or 4
  constexpr int MF2 = MF/2;
  constexpr int ABUF = 32768;
  constexpr int BBUF = BN*128;
  constexpr int BHALF = BBUF/2;             // 16384 or 8192
  constexpr int RB = BHALF/128;             // 128 or 64 rows per B-half
  constexpr int LB = BHALF/8192;            // 2 or 1 loads/thread per B-half
  constexpr int BUFSZ = ABUF + BBUF;
  extern __shared__ char smem[];

  const int bz = blockIdx.z;
  const short* Ab = A + bz*sA;
  const short* Bb = Bw + bz*sB;
  const int m0 = blockIdx.x*256, n0 = blockIdx.y*BN;
  const int t = threadIdx.x;
  const int lane = t & 63, wid = t >> 6;
  const int g = lane >> 4, lr = lane & 15;
  const int wr = wid / WARPS_N, wc = wid % WARPS_N;
  const long long KdLL = Kd;

  // staging source (pre-swizzled): thread t stages chunk (t&7)^(row&7) of row t>>3
  const int r0 = t >> 3;
  const int c0s = ((t & 7) ^ (r0 & 7)) * 8;
  const short* pA0 = Ab + (long long)(m0 + r0)*KdLL + c0s;
  const short* pB0 = Bb + (long long)(n0 + r0)*KdLL + c0s;

  // ds_read offsets (within a buffer), swizzled chunk per (frag,ks)
  int roA[MF], swA[MF], roB[4], swB[4];
  #pragma unroll
  for (int mf = 0; mf < MF; mf++){
    int ra = wr*WM + mf*16 + lr;
    roA[mf] = (ra>>7)*16384 + (ra&127)*128;
    swA[mf] = ra & 7;
  }
  #pragma unroll
  for (int nf = 0; nf < 4; nf++){
    int cb = wc*WN + nf*16 + lr;
    roB[nf] = ABUF + (cb/RB)*BHALF + (cb%RB)*128;
    swB[nf] = cb & 7;
  }

  f32x4 acc[MF][4];
  #pragma unroll
  for (int i = 0; i < MF; i++)
    #pragma unroll
    for (int j = 0; j < 4; j++)
      acc[i][j] = f32x4{0.f,0.f,0.f,0.f};
  bf16x8 av[MF2][2], bv[4][2];

  char* b0 = smem;
  char* b1 = smem + BUFSZ;
  const int NT = Kd >> 6;      // K-tiles (even, >= 4)
  const int NT2 = NT >> 1;

  // prologue: kt=0 fully, kt=1 B-halves; leave B(kt1) in flight
  STAGE_A(0,0,0); STAGE_A(0,1,0);
  STAGE_B(0,0,0); STAGE_B(0,1,0);
  STAGE_B(1,0,1); STAGE_B(1,1,1);
  WAITV_STEADY();
  __builtin_amdgcn_sched_barrier(0);
  __builtin_amdgcn_s_barrier();

  for (int it2 = 0; it2 < NT2; ++it2){
    const int kt0 = it2*2, kt1 = kt0 + 1;
    const bool more = (it2 + 1 < NT2);
    // ---- K-tile kt0 from buf0 ----
    // ph1
    READ_A8(0, b0); READ_B4(0, b0);
    STAGE_A(1, 0, kt1);
    PH_BEGIN(); MFMA_Q(0,0); PH_END();
    // ph2
    READ_B4(1, b0);
    STAGE_A(1, 1, kt1);
    PH_BEGIN(); MFMA_Q(0,1); PH_END();
    // ph3
    READ_A8(1, b0);
    if (more) STAGE_B(0, 0, kt0+2);
    PH_BEGIN(); MFMA_Q(1,0); PH_END();
    // ph4
    if (more) STAGE_B(0, 1, kt0+2);
    PH_BEGIN(); MFMA_Q(1,1);
    __builtin_amdgcn_s_setprio(0);
    if (more) WAITV_STEADY();
    else      asm volatile("s_waitcnt vmcnt(0)" ::: "memory");
    __builtin_amdgcn_sched_barrier(0);
    __builtin_amdgcn_s_barrier();
    // ---- K-tile kt1 from buf1 ----
    // ph5
    READ_A8(0, b1); READ_B4(0, b1);
    if (more) STAGE_A(0, 0, kt0+2);
    PH_BEGIN(); MFMA_Q(0,0); PH_END();
    // ph6
    READ_B4(1, b1);
    if (more) STAGE_A(0, 1, kt0+2);
    PH_BEGIN(); MFMA_Q(0,1); PH_END();
    // ph7
    READ_A8(1, b1);
    if (more) STAGE_B(1, 0, kt1+2);
    PH_BEGIN(); MFMA_Q(1,0); PH_END();
    // ph8
    if (more) STAGE_B(1, 1, kt1+2);
    PH_BEGIN(); MFMA_Q(1,1);
    __builtin_amdgcn_s_setprio(0);
    if (more) WAITV_STEADY();
    else      asm volatile("s_waitcnt vmcnt(0)" ::: "memory");
    __builtin_amdgcn_sched_barrier(0);
    __builtin_amdgcn_s_barrier();
  }

  // epilogue: swapped-operand layout -> row = lane dim, 4 consecutive cols/reg
  short* outb = outp + bz*sO;
  #pragma unroll
  for (int mi = 0; mi < MF; mi++){
    int row = m0 + wr*WM + mi*16 + lr;
    #pragma unroll
    for (int ni = 0; ni < 4; ni++){
      int col = n0 + wc*WN + ni*16 + g*4;
      bf16x4 pk;
      #pragma unroll
      for (int i = 0; i < 4; i++) pk[i] = f2bf(acc[mi][ni][i]*scale);
      *(bf16x4*)&outb[(long long)row*Nn + col] = pk;
    }
  }
}

// ============ round-3 pipeline GEMM kept for QKV / O-proj (small K) ===========
template<int MODE, int BN>
__global__ __launch_bounds__(512, 2) void gemm256(
    const short* __restrict__ A, const short* __restrict__ Bw,
    const float* __restrict__ bias,
    void* __restrict__ outp, const float* __restrict__ resid,
    int M, int Nn, int Kd,
    long long sA, long long sB, long long sO, float scale)
{
  constexpr int BROUNDS = BN/64;
  constexpr int LOADS   = 4 + BROUNDS;
  constexpr int WM = (BN==256) ? 128 : 64;
  constexpr int WN = 64;
  constexpr int WAVES_N = BN/WN;
  constexpr int MF = WM/16, NF = WN/16;
  constexpr int ASZ = 32768, BSZ = BN*128;
  extern __shared__ char smem[];

  const int bz = blockIdx.z;
  const short* Ab = A + bz*sA;
  const short* Bb = Bw + bz*sB;
  const int m0 = blockIdx.x*256, n0 = blockIdx.y*BN;
  const int t = threadIdx.x;
  const int lane = t & 63, wid = t >> 6;
  const int g = lane >> 4, lr = lane & 15;
  const int wr = wid / WAVES_N, wc = wid % WAVES_N;

  const int rsub = t >> 3;
  const int chunkEl = (((t & 7) ^ (rsub & 7))) * 8;
  const short* gA[4]; const short* gB[BROUNDS];
  #pragma unroll
  for (int j = 0; j < 4; j++)
    gA[j] = Ab + (long long)(m0 + j*64 + rsub)*Kd + chunkEl;
  #pragma unroll
  for (int j = 0; j < BROUNDS; j++)
    gB[j] = Bb + (long long)(n0 + j*64 + rsub)*Kd + chunkEl;
  const int tb = t*16;

  const int rowAbyte = (wr*WM + lr)*128;
  const int rowBbyte = (wc*WN + lr)*128;
  const int ch0 = ((g)     ^ (lr & 7)) << 4;
  const int ch1 = ((4 + g) ^ (lr & 7)) << 4;

  f32x4 acc[MF][NF];
  #pragma unroll
  for (int i = 0; i < MF; i++)
    #pragma unroll
    for (int j = 0; j < NF; j++)
      acc[i][j] = f32x4{0.f,0.f,0.f,0.f};

  const int NT = Kd >> 6;

  auto STAGE = [&](int tile, int buf){
    char* base = smem + buf*(ASZ+BSZ);
    const int kt = tile*64;
    #pragma unroll
    for (int j = 0; j < 4; j++)
      gload_lds16(gA[j] + kt, base + j*8192 + tb);
    #pragma unroll
    for (int j = 0; j < BROUNDS; j++)
      gload_lds16(gB[j] + kt, base + ASZ + j*8192 + tb);
  };

  STAGE(0, 0);
  STAGE(1, 1);
  if constexpr (LOADS == 8) asm volatile("s_waitcnt vmcnt(8)" ::: "memory");
  else                      asm volatile("s_waitcnt vmcnt(6)" ::: "memory");
  __builtin_amdgcn_s_barrier();

  for (int it = 0; it < NT; ++it){
    char* base = smem + (it & 1)*(ASZ+BSZ);
    bf16x8 av[MF][2], bv[NF][2];
    #pragma unroll
    for (int ni = 0; ni < NF; ni++){
      bv[ni][0] = *(const bf16x8*)(base + ASZ + rowBbyte + ni*2048 + ch0);
      bv[ni][1] = *(const bf16x8*)(base + ASZ + rowBbyte + ni*2048 + ch1);
    }
    #pragma unroll
    for (int mi = 0; mi < MF; mi++){
      av[mi][0] = *(const bf16x8*)(base + rowAbyte + mi*2048 + ch0);
      av[mi][1] = *(const bf16x8*)(base + rowAbyte + mi*2048 + ch1);
    }
    asm volatile("s_waitcnt lgkmcnt(0)" ::: "memory");
    __builtin_amdgcn_sched_barrier(0);
    __builtin_amdgcn_s_barrier();

    if (it + 2 < NT) STAGE(it + 2, it & 1);

    #pragma unroll
    for (int mi = 0; mi < MF; mi++)
      #pragma unroll
      for (int ni = 0; ni < NF; ni++)
        #pragma unroll
        for (int ks = 0; ks < 2; ks++){
          if constexpr (MODE == 0)
            acc[mi][ni] = __builtin_amdgcn_mfma_f32_16x16x32_bf16(bv[ni][ks], av[mi][ks], acc[mi][ni], 0, 0, 0);
          else
            acc[mi][ni] = __builtin_amdgcn_mfma_f32_16x16x32_bf16(av[mi][ks], bv[ni][ks], acc[mi][ni], 0, 0, 0);
        }

    if (it + 2 < NT){
      if constexpr (LOADS == 8) asm volatile("s_waitcnt vmcnt(8)" ::: "memory");
      else                      asm volatile("s_waitcnt vmcnt(6)" ::: "memory");
    } else {
      asm volatile("s_waitcnt vmcnt(0)" ::: "memory");
    }
    __builtin_amdgcn_s_barrier();
  }

  if constexpr (MODE == 0){
    short* outb = (short*)outp + bz*sO;
    const bool hb = (bias != nullptr);
    #pragma unroll
    for (int mi = 0; mi < MF; mi++){
      int row = m0 + wr*WM + mi*16 + lr;
      #pragma unroll
      for (int ni = 0; ni < NF; ni++){
        int col = n0 + wc*WN + ni*16 + g*4;
        float b0=0.f,b1=0.f,b2=0.f,b3=0.f;
        if (hb){ float4 bb = *(const float4*)&bias[col]; b0=bb.x; b1=bb.y; b2=bb.z; b3=bb.w; }
        bf16x4 pk;
        pk[0] = f2bf((acc[mi][ni][0] + b0)*scale);
        pk[1] = f2bf((acc[mi][ni][1] + b1)*scale);
        pk[2] = f2bf((acc[mi][ni][2] + b2)*scale);
        pk[3] = f2bf((acc[mi][ni][3] + b3)*scale);
        *(bf16x4*)&outb[(long long)row*Nn + col] = pk;
      }
    }
  } else if constexpr (MODE == 1){
    short* outb = (short*)outp + bz*sO;
    #pragma unroll
    for (int ni = 0; ni < NF; ni++){
      int col = n0 + wc*WN + ni*16 + lr;
      float bv2 = bias ? bias[col] : 0.f;
      #pragma unroll
      for (int mi = 0; mi < MF; mi++){
        int row = m0 + wr*WM + mi*16 + g*4;
        bf16x4 pk;
        #pragma unroll
        for (int i = 0; i < 4; i++) pk[i] = f2bf((acc[mi][ni][i] + bv2)*scale);
        *(bf16x4*)&outb[(long long)col*M + row] = pk;
      }
    }
  } else {
    float* outb = (float*)outp + bz*sO;
    const float* rx = resid + bz*sO;
    #pragma unroll
    for (int ni = 0; ni < NF; ni++){
      int col = n0 + wc*WN + ni*16 + lr;
      float bv2 = bias[col];
      #pragma unroll
      for (int mi = 0; mi < MF; mi++){
        int row = m0 + wr*WM + mi*16 + g*4;
        long long off = (long long)col*M + row;
        float4 xr = *(const float4*)&rx[off];
        float4 o;
        o.x = acc[mi][ni][0] + bv2 + xr.x;
        o.y = acc[mi][ni][1] + bv2 + xr.y;
        o.z = acc[mi][ni][2] + bv2 + xr.z;
        o.w = acc[mi][ni][3] + bv2 + xr.w;
        *(float4*)&outb[off] = o;
      }
    }
  }
}

extern "C" void kernel_launch(void* const* d_in, const int* in_sizes, int n_in,
                              void* d_out, int out_size, void* d_ws, size_t ws_size,
                              hipStream_t stream)
{
  const float* x   = (const float*)d_in[0];
  const float* gnw = (const float*)d_in[1];
  const float* gnb = (const float*)d_in[2];
  const float* Wq  = (const float*)d_in[3];
  const float* bq  = (const float*)d_in[4];
  const float* Wk  = (const float*)d_in[5];
  const float* bk  = (const float*)d_in[6];
  const float* Wv  = (const float*)d_in[7];
  const float* bvp = (const float*)d_in[8];
  const float* Wo  = (const float*)d_in[9];
  const float* bo  = (const float*)d_in[10];
  float* out = (float*)d_out;

  char* ws = (char*)d_ws;
  const size_t MB = 1ull << 20;
  short* h    = (short*)(ws);
  short* q    = (short*)(ws + 16*MB);
  short* kmat = (short*)(ws + 32*MB);
  short* vt   = (short*)(ws + 48*MB);
  short* ao   = (short*)(ws + 64*MB);
  short* wqb  = (short*)(ws + 80*MB);
  short* wkb  = wqb + 262144;
  short* wvb  = wkb + 262144;
  short* wob  = wvb + 262144;
  float* stats= (float*)(ws + 82*MB);
  short* S    = (short*)(ws + 84*MB);   // 128 MB (full path)

  const int LDS8P256 = 131072, LDS8P128 = 98304, LDS128 = 98304;
  hipFuncSetAttribute(reinterpret_cast<const void*>(&gemm8p<256>),
                      hipFuncAttributeMaxDynamicSharedMemorySize, LDS8P256);
  hipFuncSetAttribute(reinterpret_cast<const void*>(&gemm8p<128>),
                      hipFuncAttributeMaxDynamicSharedMemorySize, LDS8P128);
  hipFuncSetAttribute(reinterpret_cast<const void*>(&gemm256<0,128>),
                      hipFuncAttributeMaxDynamicSharedMemorySize, LDS128);
  hipFuncSetAttribute(reinterpret_cast<const void*>(&gemm256<1,128>),
                      hipFuncAttributeMaxDynamicSharedMemorySize, LDS128);
  hipFuncSetAttribute(reinterpret_cast<const void*>(&gemm256<2,128>),
                      hipFuncAttributeMaxDynamicSharedMemorySize, LDS128);

  dim3 blk(256);
  dim3 blk512(512);
  gn_stats<<<dim3(128), blk, 0, stream>>>(x, stats);
  gn_apply<<<dim3(64,4), blk, 0, stream>>>(x, stats, gnw, gnb, h);
  f2bf_all<<<dim3(512), blk, 0, stream>>>(Wq, Wk, Wv, Wo, wqb, wkb, wvb, wob);

  const long long sTok = 4096ll*512;
  const float qscale = 0.044194173824159216f;  // 1/sqrt(512)

  // Q (scale folded), K, V(transposed out)
  gemm256<0,128><<<dim3(16,4,4), blk512, LDS128, stream>>>(h, wqb, bq,  q,    nullptr, 4096, 512, 512, sTok, 0, sTok, qscale);
  gemm256<0,128><<<dim3(16,4,4), blk512, LDS128, stream>>>(h, wkb, bk,  kmat, nullptr, 4096, 512, 512, sTok, 0, sTok, 1.f);
  gemm256<1,128><<<dim3(16,4,4), blk512, LDS128, stream>>>(h, wvb, bvp, vt,   nullptr, 4096, 512, 512, sTok, 0, sTok, 1.f);

  if (ws_size >= 212*MB){
    gemm8p<256><<<dim3(16,16,4), blk512, LDS8P256, stream>>>(q, kmat, S, 4096, 512, sTok, sTok, 4096ll*4096, 1.f);
    softmax_rows<<<dim3(16384), blk, 0, stream>>>(S);
    gemm8p<128><<<dim3(16,4,4), blk512, LDS8P128, stream>>>(S, vt, ao, 512, 4096, 4096ll*4096, sTok, sTok, 1.f);
  } else {
    for (int b = 0; b < 4; b++){
      gemm8p<256><<<dim3(16,16,1), blk512, LDS8P256, stream>>>(q + b*sTok, kmat + b*sTok, S, 4096, 512, 0, 0, 0, 1.f);
      softmax_rows<<<dim3(4096), blk, 0, stream>>>(S);
      gemm8p<128><<<dim3(16,4,1), blk512, LDS8P128, stream>>>(S, vt + b*sTok, ao + b*sTok, 512, 4096, 0, 0, 0, 1.f);
    }
  }

  // O-projection + bias + residual + transpose to [B, C, N] fp32
  gemm256<2,128><<<dim3(16,4,4), blk512, LDS128, stream>>>(ao, wob, bo, out, x, 4096, 512, 512, sTok, 0, sTok, 1.f);
}